// Round 10
// baseline (332.300 us; speedup 1.0000x reference)
//
#include <hip/hip_runtime.h>
#include <math.h>

// ---------------------------------------------------------------------------
// Sinkhorn ETP (FASTopic) on MI355X.
// n=256 topics, m=32768 words, D=384.
//
//   log_K0[i,j] = G[i,j] + su0[i] + sv0[j],  G = 40 * x@y^T
//   Per iteration:  W[j] = log_b - lse_i(G+su);  su'[i] = log_a - lse_j(G+W)
//   Final: transp[i,j] = exp(G+su[i]+W[j]); M = nx[i]+ny[j]-0.05*G;
//          loss = sum(transp*M)
//
// R16 (WIN 383->308): persistent iteration kernel, register-resident tile,
// device-scope generation barrier, fused convergence.
// R17 (FAIL 326): fusing gemm+finalize was right, but the fragment->tile
// layout conversion made acc[4][8] (128 VGPR) and tile[32] (128 VGPR)
// simultaneously live -> ~1KB/thread scratch spill (WRITE 101MB vs 34
// expected, FETCH +17MB, symmetric round-trip signature) + 2.2M LDS bank
// conflicts in the conversion buffer.
//
// R18: DELETE the conversion. Iterations run directly on the MFMA fragment
// layout: thread (w,q,l15) owns rows R(mi,r)=64w+16mi+4q+r x cols
// C(nj)=16nj+l15 (= acc[4][8], the only big register array, pinned).
// Column partials: per-thread over 16 rows -> mm/ss[16][132] -> t<128 merge
// (exact lse iter-1 / E-reuse fast path, math regrouped but same algorithm).
// Row partials: per-thread over 8 cols -> pq[R*17+l15] -> thread t reduces
// row t -> cross-block combine VERBATIM from R16/R17. E recomputed in the
// row pass (~128 extra v_exp/thread ~0.4us/iter) instead of stored - the
// explicit trade that avoids a second 128-reg array. Finalize reads acc.
// Predicted: fused_k 250 -> 150-185us, WRITE 101 -> ~35MB, no spill;
// total ~200-225us. Falsifiers: WRITE high w/o spill -> NT amplification
// (switch to plain stores); per-iter balloons -> VALU-bound exps.
// ---------------------------------------------------------------------------

#define N_TOPIC 256
#define N_WORD  32768

static constexpr float LOG_A = -5.545177444479562f;    // log(1/256 + 1e-30)
static constexpr float LOG_B = -10.397207708399179f;   // log(1/32768 + 1e-30)
static constexpr float BVAL  = 3.0517578125e-05f;      // 1/32768

typedef float f32x4 __attribute__((ext_vector_type(4)));
typedef short bf16x8 __attribute__((ext_vector_type(8)));

#define PINV(v) asm volatile("" : "+v"((v)[0]), "+v"((v)[1]), "+v"((v)[2]), "+v"((v)[3]))

// ---------------------------------------------------------------- init ------
__global__ __launch_bounds__(256) void init_k(
    const float* __restrict__ x, const float* __restrict__ y,
    float* __restrict__ nx, float* __restrict__ ny, float* __restrict__ su,
    unsigned* __restrict__ colerr, int* __restrict__ active,
    int* __restrict__ counters, float* __restrict__ out)
{
    const int b = blockIdx.x, t = threadIdx.x;
    const int w = t >> 6, l = t & 63;
    if (b < 8192) {                       // ||y_j||^2, 4 rows/block (wave per row)
        const int r = (b << 2) + w;
        const float4* y4 = (const float4*)y;
        float4 v = y4[r * 96 + l];
        float s = v.x * v.x + v.y * v.y + v.z * v.z + v.w * v.w;
        if (l < 32) {
            float4 u = y4[r * 96 + 64 + l];
            s += u.x * u.x + u.y * u.y + u.z * u.z + u.w * u.w;
        }
        for (int off = 32; off; off >>= 1) s += __shfl_down(s, off);
        if (l == 0) ny[r] = s;
    } else if (b < 8256) {                // ||x_i||^2 and su0 = -20*nx
        const int r = ((b - 8192) << 2) + w;
        const float4* x4 = (const float4*)x;
        float4 v = x4[r * 96 + l];
        float s = v.x * v.x + v.y * v.y + v.z * v.z + v.w * v.w;
        if (l < 32) {
            float4 u = x4[r * 96 + 64 + l];
            s += u.x * u.x + u.y * u.y + u.z * u.z + u.w * u.w;
        }
        for (int off = 32; off; off >>= 1) s += __shfl_down(s, off);
        if (l == 0) { nx[r] = s; su[r] = -20.f * s; }
    } else {
        for (int k = t; k < 4096; k += 256) counters[k] = 0;
        if (t == 0) { colerr[0] = 0u; colerr[1] = 0u; active[0] = 1; out[0] = 0.f; }
    }
}

// Exact 3-way bf16 truncation split: v = b0 + b1 + b2 (+ r3, |r3|<=2^-27|v|).
static __device__ __forceinline__ void split3(float v, ushort& h0, ushort& h1, ushort& h2)
{
    unsigned u0 = __float_as_uint(v);
    h0 = (ushort)(u0 >> 16);
    float r1 = v - __uint_as_float(u0 & 0xFFFF0000u);
    unsigned u1 = __float_as_uint(r1);
    h1 = (ushort)(u1 >> 16);
    float r2 = r1 - __uint_as_float(u1 & 0xFFFF0000u);
    h2 = (ushort)(__float_as_uint(r2) >> 16);
}

// ----------------------------------------------- persistent barrier ---------
static __device__ __forceinline__ bool bar_arrive(int* cnt, int ph, int t, int* lastf)
{
    __threadfence();
    if (t == 0) *lastf = (atomicAdd(&cnt[ph], 1) == 255);
    __syncthreads();
    return *lastf != 0;
}
static __device__ __forceinline__ void bar_release(int* gen, int ph, int t)
{
    __threadfence();
    if (t == 0) atomicExch(gen, ph);
}
static __device__ __forceinline__ void bar_wait(int* gen, int ph, int t)
{
    if (t == 0) {
        while (atomicCAS(gen, -1, -1) < ph) __builtin_amdgcn_s_sleep(2);
    }
    __syncthreads();
    __threadfence();
}

// --------------------------------- fused gemm + Sinkhorn + finalize ---------
// 256 blocks x 256 threads, 1 block/CU. Block b owns cols [128b,128b+128).
// Phase A: MFMA G-tile (256x128) into acc[4][8]; acc *= 40 -> acc IS G.
// Phase C: iterations in fragment layout. Phase D: fused finalize from acc.
// Thread (w=t>>6, q=(t&63)>>4, l15=t&15): rows R(mi,r)=64w+16mi+4q+r,
// local cols C(nj)=16nj+l15; acc[mi][nj][r] = G[R][C].
__global__ __launch_bounds__(256, 1) void fused_k(
    const float* __restrict__ x, const float* __restrict__ y,
    float* __restrict__ su, const float* __restrict__ nx,
    const float* __restrict__ ny, float2* __restrict__ pms,
    float* __restrict__ prow, int* __restrict__ cnt, int* __restrict__ gen,
    unsigned* __restrict__ colerr, int* __restrict__ active,
    float* __restrict__ out)
{
    __shared__ __align__(16) char smem[63488];
    __shared__ int lastf;
    // gemm-phase region
    float4* xs4 = (float4*)smem;                  // [256 rows][8 slots] 32768B
    ushort* ys0 = (ushort*)(smem + 32768);        // [128][40] 10240B
    ushort* ys1 = (ushort*)(smem + 43008);
    ushort* ys2 = (ushort*)(smem + 53248);        // ends 63488
    // iteration/finalize region (alive after Phase A)
    float* su_lds = (float*)smem;                 // 256f        @0
    float* mm    = (float*)(smem + 1024);         // [16][132]   @1024  (8448B)
    float* ss    = (float*)(smem + 9472);         // [16][132]   @9472  (8448B)
    float* Mcol  = (float*)(smem + 17920);        // 128f
    float* Wlds  = (float*)(smem + 18432);        // 128f
    float* ecol  = (float*)(smem + 18944);        // 128f
    float* Rlds  = (float*)(smem + 19456);        // 256f
    float* errb  = (float*)(smem + 20480);        // 128f
    float* nxl   = (float*)(smem + 20992);        // 256f
    float* nyl   = (float*)(smem + 22016);        // 128f
    float* pq    = (float*)(smem + 22528);        // [256][17]f (17408B) ->39936

    const int t   = threadIdx.x;
    const int b   = blockIdx.x;
    const int w   = t >> 6, ln = t & 63, q = ln >> 4, l15 = ln & 15;
    const int g16 = (w << 2) + q;      // partial-group 0..15
    const int jy0 = b << 7;
    int ph = 1;

    const float4* x4 = (const float4*)x;
    const float4* y4 = (const float4*)y;

#define ROW(mi, r) ((w << 6) + ((mi) << 4) + (q << 2) + (r))

    // ================= Phase A: G-tile by MFMA =================
    f32x4 acc[4][8];
#pragma unroll
    for (int mi = 0; mi < 4; ++mi)
#pragma unroll
        for (int nj = 0; nj < 8; ++nj) acc[mi][nj] = (f32x4){0.f, 0.f, 0.f, 0.f};

    for (int kc = 0; kc < 12; ++kc) {
        __syncthreads();
        // stage x: 256 rows x 8 float4-slots, XOR-swizzled (slot ^= row&7)
#pragma unroll
        for (int p = 0; p < 8; ++p) {
            const int f = (p << 8) + t;          // 0..2047
            const int r = f >> 3, c4 = f & 7;
            xs4[(r << 3) + (c4 ^ (r & 7))] = x4[r * 96 + (kc << 3) + c4];
        }
        // stage y slab rows [128b,128b+128) with 3-way bf16 split
#pragma unroll
        for (int p = 0; p < 4; ++p) {
            const int f = (p << 8) + t;          // 0..1023
            const int r = f >> 3, c4 = f & 7;
            float4 vy = y4[(size_t)(jy0 + r) * 96 + (kc << 3) + c4];
            ushort a0,a1,a2,b0,b1,b2,g0,g1,g2,d0,d1,d2;
            split3(vy.x, a0,a1,a2); split3(vy.y, b0,b1,b2);
            split3(vy.z, g0,g1,g2); split3(vy.w, d0,d1,d2);
            *(ushort4*)&ys0[r * 40 + (c4 << 2)] = make_ushort4(a0,b0,g0,d0);
            *(ushort4*)&ys1[r * 40 + (c4 << 2)] = make_ushort4(a1,b1,g1,d1);
            *(ushort4*)&ys2[r * 40 + (c4 << 2)] = make_ushort4(a2,b2,g2,d2);
        }
        __syncthreads();

        // A fragments: row = 64w + 16mi + l15, k-offset q*8 (split on the fly)
        union U8 { ushort u[8]; bf16x8 v; };
        bf16x8 A0[4], A1[4], A2[4];
#pragma unroll
        for (int mi = 0; mi < 4; ++mi) {
            const int row = (w << 6) + (mi << 4) + l15;
            const int base = row << 3;
            float4 xa = xs4[base + (((q << 1) + 0) ^ (row & 7))];
            float4 xb = xs4[base + (((q << 1) + 1) ^ (row & 7))];
            U8 u0, u1, u2;
            split3(xa.x, u0.u[0], u1.u[0], u2.u[0]);
            split3(xa.y, u0.u[1], u1.u[1], u2.u[1]);
            split3(xa.z, u0.u[2], u1.u[2], u2.u[2]);
            split3(xa.w, u0.u[3], u1.u[3], u2.u[3]);
            split3(xb.x, u0.u[4], u1.u[4], u2.u[4]);
            split3(xb.y, u0.u[5], u1.u[5], u2.u[5]);
            split3(xb.z, u0.u[6], u1.u[6], u2.u[6]);
            split3(xb.w, u0.u[7], u1.u[7], u2.u[7]);
            A0[mi] = u0.v; A1[mi] = u1.v; A2[mi] = u2.v;
        }
#pragma unroll
        for (int nj = 0; nj < 8; ++nj) {
            const int off = ((nj << 4) + l15) * 40 + (q << 3);
            bf16x8 B0 = *(const bf16x8*)&ys0[off];
            bf16x8 B1 = *(const bf16x8*)&ys1[off];
            bf16x8 B2 = *(const bf16x8*)&ys2[off];
#pragma unroll
            for (int mi = 0; mi < 4; ++mi) {
                f32x4 c = acc[mi][nj];
                c = __builtin_amdgcn_mfma_f32_16x16x32_bf16(A0[mi], B0, c, 0, 0, 0);
                c = __builtin_amdgcn_mfma_f32_16x16x32_bf16(A0[mi], B1, c, 0, 0, 0);
                c = __builtin_amdgcn_mfma_f32_16x16x32_bf16(A1[mi], B0, c, 0, 0, 0);
                c = __builtin_amdgcn_mfma_f32_16x16x32_bf16(A1[mi], B1, c, 0, 0, 0);
                c = __builtin_amdgcn_mfma_f32_16x16x32_bf16(A0[mi], B2, c, 0, 0, 0);
                c = __builtin_amdgcn_mfma_f32_16x16x32_bf16(A2[mi], B0, c, 0, 0, 0);
                acc[mi][nj] = c;
            }
        }
    }
    // scale: acc IS G (40 * x@y^T)
#pragma unroll
    for (int mi = 0; mi < 4; ++mi)
#pragma unroll
        for (int nj = 0; nj < 8; ++nj) {
            acc[mi][nj] = acc[mi][nj] * 40.f;
            PINV(acc[mi][nj]);
        }

    __syncthreads();                  // staging dead; iteration region begins
    su_lds[t] = su[t];                // su0 = -20*|x|^2
    __syncthreads();

    // ================= Phase C: iterations (fragment layout) ==============
    // ---- iteration 1 (log-safe, exact lse) ----
    {
#pragma unroll
        for (int nj = 0; nj < 8; ++nj) {
            const int C = (nj << 4) + l15;
            float m = -INFINITY;
#pragma unroll
            for (int mi = 0; mi < 4; ++mi)
#pragma unroll
                for (int r = 0; r < 4; ++r)
                    m = fmaxf(m, acc[mi][nj][r] + su_lds[ROW(mi, r)]);
            float s = 0.f;
#pragma unroll
            for (int mi = 0; mi < 4; ++mi)
#pragma unroll
                for (int r = 0; r < 4; ++r)
                    s += __expf(acc[mi][nj][r] + su_lds[ROW(mi, r)] - m);
            mm[g16 * 132 + C] = m;
            ss[g16 * 132 + C] = s;
        }
        __syncthreads();
        if (t < 128) {
            float m = -INFINITY, s = 0.f;
#pragma unroll
            for (int g = 0; g < 16; ++g) {
                float pmv = mm[g * 132 + t], psv = ss[g * 132 + t];
                float nm = fmaxf(m, pmv);
                s = s * __expf(m - nm) + psv * __expf(pmv - nm);
                m = nm;
            }
            Wlds[t] = LOG_B - (m + __logf(s));
        }
        __syncthreads();
    }
    // row pass (exact): rowmax, then expsum; cross-block lse combine
    {
        float rm[4][4];
#pragma unroll
        for (int mi = 0; mi < 4; ++mi)
#pragma unroll
            for (int r = 0; r < 4; ++r) rm[mi][r] = -INFINITY;
#pragma unroll
        for (int nj = 0; nj < 8; ++nj) {
            const float Wc = Wlds[(nj << 4) + l15];
#pragma unroll
            for (int mi = 0; mi < 4; ++mi)
#pragma unroll
                for (int r = 0; r < 4; ++r)
                    rm[mi][r] = fmaxf(rm[mi][r], acc[mi][nj][r] + Wc);
        }
#pragma unroll
        for (int mi = 0; mi < 4; ++mi)
#pragma unroll
            for (int r = 0; r < 4; ++r)
                pq[ROW(mi, r) * 17 + l15] = rm[mi][r];
        __syncthreads();
        {
            float R = -INFINITY;
#pragma unroll
            for (int p = 0; p < 16; ++p) R = fmaxf(R, pq[t * 17 + p]);
            Rlds[t] = R;
        }
        __syncthreads();
        float rs[4][4];
#pragma unroll
        for (int mi = 0; mi < 4; ++mi)
#pragma unroll
            for (int r = 0; r < 4; ++r) rs[mi][r] = 0.f;
#pragma unroll
        for (int nj = 0; nj < 8; ++nj) {
            const float Wc = Wlds[(nj << 4) + l15];
#pragma unroll
            for (int mi = 0; mi < 4; ++mi)
#pragma unroll
                for (int r = 0; r < 4; ++r)
                    rs[mi][r] += __expf(acc[mi][nj][r] + Wc - Rlds[ROW(mi, r)]);
        }
#pragma unroll
        for (int mi = 0; mi < 4; ++mi)
#pragma unroll
            for (int r = 0; r < 4; ++r)
                pq[ROW(mi, r) * 17 + l15] = rs[mi][r];
        __syncthreads();
        {
            float s = 0.f;
#pragma unroll
            for (int p = 0; p < 16; ++p) s += pq[t * 17 + p];
            pms[(b << 8) + t] = make_float2(Rlds[t], s);
        }
    }
    if (bar_arrive(cnt, ph, t, &lastf)) {
        __threadfence();
        float m = -INFINITY, s = 0.f;
        for (int p = 0; p < 256; ++p) {
            float2 v = pms[(p << 8) + t];
            float nm = fmaxf(m, v.x);
            s = s * __expf(m - nm) + v.y * __expf(v.x - nm);
            m = nm;
        }
        su[t] = LOG_A - (m + __logf(s));
        bar_release(gen, ph, t);
    }
    bar_wait(gen, ph, t); ++ph;
    su_lds[t] = su[t];
    __syncthreads();

    // ---- convergence check #1 (ref cpt_n=1): col marginal err vs b ----
    int act;
    {
#pragma unroll
        for (int nj = 0; nj < 8; ++nj) {
            const int C = (nj << 4) + l15;
            float m = -INFINITY;
#pragma unroll
            for (int mi = 0; mi < 4; ++mi)
#pragma unroll
                for (int r = 0; r < 4; ++r)
                    m = fmaxf(m, acc[mi][nj][r] + su_lds[ROW(mi, r)]);
            float s = 0.f;
#pragma unroll
            for (int mi = 0; mi < 4; ++mi)
#pragma unroll
                for (int r = 0; r < 4; ++r)
                    s += __expf(acc[mi][nj][r] + su_lds[ROW(mi, r)] - m);
            mm[g16 * 132 + C] = m;
            ss[g16 * 132 + C] = s;
        }
        __syncthreads();
        if (t < 128) {
            float m = -INFINITY, s = 0.f;
#pragma unroll
            for (int g = 0; g < 16; ++g) {
                float pmv = mm[g * 132 + t], psv = ss[g * 132 + t];
                float nm = fmaxf(m, pmv);
                s = s * __expf(m - nm) + psv * __expf(pmv - nm);
                m = nm;
            }
            errb[t] = fabsf(__expf((m + __logf(s)) + Wlds[t]) - BVAL);
        }
        __syncthreads();
        for (int n = 64; n; n >>= 1) {
            if (t < n) errb[t] = fmaxf(errb[t], errb[t + n]);
            __syncthreads();
        }
        if (t == 0) atomicMax(&colerr[0], __float_as_uint(errb[0]));
        if (bar_arrive(cnt, ph, t, &lastf)) {
            if (t == 0) {
                unsigned e = atomicMax(&colerr[0], 0u);
                active[0] = (__uint_as_float(e) > 0.005f) ? 1 : 0;
            }
            bar_release(gen, ph, t);
        }
        bar_wait(gen, ph, t); ++ph;
        act = active[0];
    }

    // ---- fast iterations 2..100 (E-reuse; E recomputed in row pass) ----
    if (act) {
#pragma unroll 1
        for (int tt = 2; tt <= 100; ++tt) {
            // col max
#pragma unroll
            for (int nj = 0; nj < 8; ++nj) {
                const int C = (nj << 4) + l15;
                float m = -INFINITY;
#pragma unroll
                for (int mi = 0; mi < 4; ++mi)
#pragma unroll
                    for (int r = 0; r < 4; ++r)
                        m = fmaxf(m, acc[mi][nj][r] + su_lds[ROW(mi, r)]);
                mm[g16 * 132 + C] = m;
            }
            __syncthreads();
            if (t < 128) {
                float m = -INFINITY;
#pragma unroll
                for (int g = 0; g < 16; ++g) m = fmaxf(m, mm[g * 132 + t]);
                Mcol[t] = m;
            }
            __syncthreads();
            // col expsum -> W, 1/S
#pragma unroll
            for (int nj = 0; nj < 8; ++nj) {
                const int C = (nj << 4) + l15;
                const float Mc = Mcol[C];
                float s = 0.f;
#pragma unroll
                for (int mi = 0; mi < 4; ++mi)
#pragma unroll
                    for (int r = 0; r < 4; ++r)
                        s += __expf(acc[mi][nj][r] + su_lds[ROW(mi, r)] - Mc);
                ss[g16 * 132 + C] = s;
            }
            __syncthreads();
            if (t < 128) {
                float ssum = 0.f;
#pragma unroll
                for (int g = 0; g < 16; ++g) ssum += ss[g * 132 + t];
                Wlds[t] = LOG_B - (Mcol[t] + __logf(ssum));
                ecol[t] = 1.0f / ssum;
            }
            __syncthreads();
            // row partial = sum_j E * (1/S)  (E recomputed)
            {
                float rp[4][4];
#pragma unroll
                for (int mi = 0; mi < 4; ++mi)
#pragma unroll
                    for (int r = 0; r < 4; ++r) rp[mi][r] = 0.f;
#pragma unroll
                for (int nj = 0; nj < 8; ++nj) {
                    const int C = (nj << 4) + l15;
                    const float Mc = Mcol[C], ec = ecol[C];
#pragma unroll
                    for (int mi = 0; mi < 4; ++mi)
#pragma unroll
                        for (int r = 0; r < 4; ++r)
                            rp[mi][r] += __expf(acc[mi][nj][r] + su_lds[ROW(mi, r)] - Mc) * ec;
                }
#pragma unroll
                for (int mi = 0; mi < 4; ++mi)
#pragma unroll
                    for (int r = 0; r < 4; ++r)
                        pq[ROW(mi, r) * 17 + l15] = rp[mi][r];
                __syncthreads();
                float s = 0.f;
#pragma unroll
                for (int p = 0; p < 16; ++p) s += pq[t * 17 + p];
                prow[(b << 8) + t] = s;
            }
            if (bar_arrive(cnt, ph, t, &lastf)) {
                __threadfence();
                float tot = 0.f;
                for (int p = 0; p < 256; ++p) tot += prow[(p << 8) + t];
                su[t] = (LOG_A - LOG_B) + su_lds[t] - __logf(tot);
                bar_release(gen, ph, t);
            }
            bar_wait(gen, ph, t); ++ph;
            su_lds[t] = su[t];
            __syncthreads();

            if (tt == 51) {
                // convergence check #2 (ref cpt_n=51)
#pragma unroll
                for (int nj = 0; nj < 8; ++nj) {
                    const int C = (nj << 4) + l15;
                    float m = -INFINITY;
#pragma unroll
                    for (int mi = 0; mi < 4; ++mi)
#pragma unroll
                        for (int r = 0; r < 4; ++r)
                            m = fmaxf(m, acc[mi][nj][r] + su_lds[ROW(mi, r)]);
                    float s = 0.f;
#pragma unroll
                    for (int mi = 0; mi < 4; ++mi)
#pragma unroll
                        for (int r = 0; r < 4; ++r)
                            s += __expf(acc[mi][nj][r] + su_lds[ROW(mi, r)] - m);
                    mm[g16 * 132 + C] = m;
                    ss[g16 * 132 + C] = s;
                }
                __syncthreads();
                if (t < 128) {
                    float m = -INFINITY, s = 0.f;
#pragma unroll
                    for (int g = 0; g < 16; ++g) {
                        float pmv = mm[g * 132 + t], psv = ss[g * 132 + t];
                        float nm = fmaxf(m, pmv);
                        s = s * __expf(m - nm) + psv * __expf(pmv - nm);
                        m = nm;
                    }
                    errb[t] = fabsf(__expf((m + __logf(s)) + Wlds[t]) - BVAL);
                }
                __syncthreads();
                for (int n = 64; n; n >>= 1) {
                    if (t < n) errb[t] = fmaxf(errb[t], errb[t + n]);
                    __syncthreads();
                }
                if (t == 0) atomicMax(&colerr[1], __float_as_uint(errb[0]));
                if (bar_arrive(cnt, ph, t, &lastf)) {
                    if (t == 0) {
                        unsigned e = atomicMax(&colerr[1], 0u);
                        active[0] = (__uint_as_float(e) > 0.005f) ? 1 : 0;
                    }
                    bar_release(gen, ph, t);
                }
                bar_wait(gen, ph, t); ++ph;
                if (active[0] == 0) break;
            }
        }
    }

    // ================= Phase D: fused finalize (from acc) =================
    nxl[t] = nx[t];
    if (t < 128) nyl[t] = ny[jy0 + t];
    __syncthreads();

    float accl = 0.f;
#pragma unroll
    for (int mi = 0; mi < 4; ++mi) {
#pragma unroll
        for (int r = 0; r < 4; ++r) {
            const int R = ROW(mi, r);
            const float si = su_lds[R], nxi = nxl[R];
            float* orow = out + 1 + (size_t)R * 32768 + jy0;
#pragma unroll
            for (int nj = 0; nj < 8; ++nj) {
                const int C = (nj << 4) + l15;
                const float g = acc[mi][nj][r];
                const float v = __expf(g + si + Wlds[C]);
                __builtin_nontemporal_store(v, orow + C);
                accl += v * (nxi + nyl[C] - 0.05f * g);
            }
        }
    }
    for (int off = 32; off; off >>= 1) accl += __shfl_down(accl, off);
    if (ln == 0) errb[w] = accl;
    __syncthreads();
    if (t == 0) atomicAdd(out, errb[0] + errb[1] + errb[2] + errb[3]);
}

// ---------------------------------------------------------------- host ------
extern "C" void kernel_launch(void* const* d_in, const int* in_sizes, int n_in,
                              void* d_out, int out_size, void* d_ws, size_t ws_size,
                              hipStream_t stream)
{
    const float* x = (const float*)d_in[0];   // [256, 384]
    const float* y = (const float*)d_in[1];   // [32768, 384]
    float* out = (float*)d_out;               // [1 + 256*32768]

    float* ws   = (float*)d_ws;
    float* su   = ws;                              // 256
    float* nx   = su + 256;                        // 256
    float* ny   = nx + 256;                        // 32768
    float2* pms = (float2*)(ny + 32768);           // 65536 float2
    float* prow = (float*)(pms + 65536);           // 65536
    unsigned* colerr = (unsigned*)(prow + 65536);  // 2
    int* active   = (int*)(colerr + 2);            // 1
    int* counters = active + 1;                    // 4096 (barrier slots + gen)
    int* gen      = counters + 3000;

    init_k<<<8257, 256, 0, stream>>>(x, y, nx, ny, su, colerr, active, counters, out);
    fused_k<<<256, 256, 0, stream>>>(x, y, su, nx, ny, pms, prow,
                                     counters, gen, colerr, active, out);
}